// Round 6
// baseline (329.955 us; speedup 1.0000x reference)
//
#include <hip/hip_runtime.h>

static constexpr int B_ = 256;
static constexpr int R_ = 1152;
static constexpr int C_ = 10;
static constexpr int O_ = 16;
static constexpr int I_ = 8;
static constexpr int SCO = C_ * O_;   // 160
static constexpr int NV = B_ * SCO;   // 40960 (= output size, (B,C,O,1))

// ---------------------------------------------------------------------------
// k_s: partial[seg][b][c][o] = sum_{r in seg} c[r,c] * (W[r,c,o,:] . x[b,r,:])
// lane = c_sub(4) x o(16); wave = 16 b's; block = (seg, cgroup(3), bquad(4)).
// W: coalesced vector loads (reused over 16 b). x: wave-uniform scalar loads.
// grid = nseg*12, XCD-swizzled on seg. Deterministic, no atomics.
// ---------------------------------------------------------------------------
__global__ __launch_bounds__(256) void k_s(const float* __restrict__ x,
                                           const float* __restrict__ W,
                                           const float* __restrict__ cvec,
                                           float* __restrict__ partial,
                                           int use_c, int nseg) {
  int seg, sub;
  const int bx = blockIdx.x;
  if ((nseg & 7) == 0) {
    const int xcd  = bx & 7;
    const int rest = bx >> 3;
    sub = rest % 12;
    seg = (rest / 12) * 8 + xcd;
  } else {
    seg = bx / 12;
    sub = bx % 12;
  }
  const int cg = sub >> 2;                    // 0..2 -> c base 0/4/8
  const int bq = sub & 3;                     // 0..3 -> b quad
  const int t    = threadIdx.x;
  const int lane = t & 63;
  const int w    = __builtin_amdgcn_readfirstlane(t >> 6);
  const int o     = lane & 15;
  const int c_sub = lane >> 4;
  const int c     = cg * 4 + c_sub;
  const bool cval = (c < C_);
  const int cl    = cval ? c : (C_ - 1);      // clamped for safe loads
  const int b0 = bq * 64 + w * 16;
  const int RT = R_ / nseg;
  const int rbase = seg * RT;

  float acc[16];
#pragma unroll
  for (int i = 0; i < 16; ++i) acc[i] = 0.0f;

  for (int rr = 0; rr < RT; ++rr) {
    const int r = rbase + rr;
    const float4* wp = (const float4*)(W + (((size_t)(r * C_ + cl)) * O_ + o) * I_);
    const float4 w0 = wp[0], w1 = wp[1];
    float cw = use_c ? cvec[r * C_ + cl] : (1.0f / 1152.0f);
    if (!cval) cw = 0.0f;
#pragma unroll
    for (int bb = 0; bb < 16; ++bb) {
      const float* xs = x + ((size_t)(b0 + bb) * R_ + r) * I_;  // uniform -> s_load
      float d = w0.x * xs[0];
      d = fmaf(w0.y, xs[1], d); d = fmaf(w0.z, xs[2], d); d = fmaf(w0.w, xs[3], d);
      d = fmaf(w1.x, xs[4], d); d = fmaf(w1.y, xs[5], d); d = fmaf(w1.z, xs[6], d);
      d = fmaf(w1.w, xs[7], d);
      acc[bb] = fmaf(cw, d, acc[bb]);
    }
  }
  if (cval) {
    float* pp = partial + (size_t)seg * NV + cg * 64 + lane;   // c*16+o == cg*64+lane
#pragma unroll
    for (int bb = 0; bb < 16; ++bb)
      pp[(size_t)(b0 + bb) * SCO] = acc[bb];
  }
}

// s = sum over segment partials; squash v = s*|s|/(1+s^2)
// (== s^3/((1+s^2)*sqrt(s^2)) for s != 0; division-safe everywhere)
__global__ __launch_bounds__(256) void k_sv(const float* __restrict__ partial,
                                            float* __restrict__ v, int nseg) {
  const int i = blockIdx.x * 256 + threadIdx.x;  // < NV
  float s = 0.0f;
  for (int g = 0; g < nseg; ++g) s += partial[(size_t)g * NV + i];
  v[i] = s * fabsf(s) / (1.0f + s * s);
}

// ---------------------------------------------------------------------------
// k_a: bpart[bq][r][c] = sum_{b in bq} sum_o (W[r,c,o,:].x[b,r,:]) * v[b,c,o]
// Same lane layout as k_s; 9 r's per block; o-reduce = 4 shfl per 144 FMA.
// grid = 128*12 = 1536, XCD-swizzled on rseg.
// ---------------------------------------------------------------------------
__global__ __launch_bounds__(256) void k_a(const float* __restrict__ x,
                                           const float* __restrict__ W,
                                           const float* __restrict__ v,
                                           float* __restrict__ bpart) {
  __shared__ float red[4][9][4];              // [wave][rr][c_sub]
  const int bx   = blockIdx.x;
  const int xcd  = bx & 7;
  const int rest = bx >> 3;
  const int sub  = rest % 12;
  const int rseg = (rest / 12) * 8 + xcd;     // 0..127
  const int cg = sub >> 2;
  const int bq = sub & 3;
  const int t    = threadIdx.x;
  const int lane = t & 63;
  const int w    = __builtin_amdgcn_readfirstlane(t >> 6);
  const int o     = lane & 15;
  const int c_sub = lane >> 4;
  const int c     = cg * 4 + c_sub;
  const bool cval = (c < C_);
  const int cl    = cval ? c : (C_ - 1);
  const int b0 = bq * 64 + w * 16;
  const int rbase = rseg * 9;

  float vf[16];
#pragma unroll
  for (int bb = 0; bb < 16; ++bb)
    vf[bb] = v[(size_t)(b0 + bb) * SCO + cl * O_ + o];

  float acc[9];
#pragma unroll
  for (int i = 0; i < 9; ++i) acc[i] = 0.0f;

#pragma unroll
  for (int rr = 0; rr < 9; ++rr) {
    const int r = rbase + rr;
    const float4* wp = (const float4*)(W + (((size_t)(r * C_ + cl)) * O_ + o) * I_);
    const float4 w0 = wp[0], w1 = wp[1];
#pragma unroll
    for (int bb = 0; bb < 16; ++bb) {
      const float* xs = x + ((size_t)(b0 + bb) * R_ + r) * I_;  // uniform -> s_load
      float d = w0.x * xs[0];
      d = fmaf(w0.y, xs[1], d); d = fmaf(w0.z, xs[2], d); d = fmaf(w0.w, xs[3], d);
      d = fmaf(w1.x, xs[4], d); d = fmaf(w1.y, xs[5], d); d = fmaf(w1.z, xs[6], d);
      d = fmaf(w1.w, xs[7], d);
      acc[rr] = fmaf(d, vf[bb], acc[rr]);
    }
  }
  // reduce over the 16 o-lanes (within each c_sub group)
#pragma unroll
  for (int rr = 0; rr < 9; ++rr) {
    float a = acc[rr];
    a += __shfl_xor(a, 1); a += __shfl_xor(a, 2);
    a += __shfl_xor(a, 4); a += __shfl_xor(a, 8);
    acc[rr] = a;
  }
  if (o == 0) {
#pragma unroll
    for (int rr = 0; rr < 9; ++rr) red[w][rr][c_sub] = acc[rr];
  }
  __syncthreads();
  if (t < 36) {
    const int rr = t >> 2, cs = t & 3;
    const int cc = cg * 4 + cs;
    if (cc < C_) {
      float s = red[0][rr][cs] + red[1][rr][cs] + red[2][rr][cs] + red[3][rr][cs];
      bpart[((size_t)bq * R_ + (rbase + rr)) * C_ + cc] = s;
    }
  }
}

// b_new = (first ? 0 : b_prev) + (sum_bq bpart)/256; cvec = softmax over r per c.
__global__ __launch_bounds__(256) void k_bc(const float* __restrict__ bpart,
                                            float* __restrict__ bvec,
                                            float* __restrict__ cvec, int first) {
  const int c = blockIdx.x;
  const int t = threadIdx.x;
  __shared__ float smx[4];
  __shared__ float sms[4];
  float bv[5];
  float mx = -3.402823466e38f;
#pragma unroll
  for (int k = 0; k < 5; ++k) {
    int r = t + k * 256;
    if (r < R_) {
      float s = bpart[(size_t)r * C_ + c]
              + bpart[((size_t)R_ + r) * C_ + c]
              + bpart[((size_t)2 * R_ + r) * C_ + c]
              + bpart[((size_t)3 * R_ + r) * C_ + c];
      float val = s * (1.0f / 256.0f);
      if (!first) val += bvec[r * C_ + c];
      bvec[r * C_ + c] = val;
      bv[k] = val;
      mx = fmaxf(mx, val);
    }
  }
  mx = fmaxf(mx, __shfl_xor(mx, 1));  mx = fmaxf(mx, __shfl_xor(mx, 2));
  mx = fmaxf(mx, __shfl_xor(mx, 4));  mx = fmaxf(mx, __shfl_xor(mx, 8));
  mx = fmaxf(mx, __shfl_xor(mx, 16)); mx = fmaxf(mx, __shfl_xor(mx, 32));
  if ((t & 63) == 0) smx[t >> 6] = mx;
  __syncthreads();
  float MX = fmaxf(fmaxf(smx[0], smx[1]), fmaxf(smx[2], smx[3]));
  float se = 0.0f;
  float ef[5];
#pragma unroll
  for (int k = 0; k < 5; ++k) {
    int r = t + k * 256;
    if (r < R_) { ef[k] = expf(bv[k] - MX); se += ef[k]; }
  }
  se += __shfl_xor(se, 1);  se += __shfl_xor(se, 2);  se += __shfl_xor(se, 4);
  se += __shfl_xor(se, 8);  se += __shfl_xor(se, 16); se += __shfl_xor(se, 32);
  if ((t & 63) == 0) sms[t >> 6] = se;
  __syncthreads();
  float inv = 1.0f / ((sms[0] + sms[1]) + (sms[2] + sms[3]));
#pragma unroll
  for (int k = 0; k < 5; ++k) {
    int r = t + k * 256;
    if (r < R_) cvec[r * C_ + c] = ef[k] * inv;
  }
}

extern "C" void kernel_launch(void* const* d_in, const int* in_sizes, int n_in,
                              void* d_out, int out_size, void* d_ws, size_t ws_size,
                              hipStream_t stream) {
  const float* x = (const float*)d_in[0];  // (B,R,I) fp32
  const float* W = (const float*)d_in[1];  // (R,C,O,I) fp32
  float* out = (float*)d_out;              // (B,C,O,1) fp32, NV elements
  float* ws = (float*)d_ws;

  // ws-adaptive segment count for k_s partials
  const long availf = (long)(ws_size / 4);
  const long fixedf = NV + 6L * (R_ * C_);   // v + bvec + cvec + bpart[4]
  long cap = (availf - fixedf) / NV;
  int nseg = 1;
  while (nseg * 2 <= 64 && (long)(nseg * 2) <= cap) nseg *= 2;

  float* partial = ws;
  float* v     = partial + (size_t)nseg * NV;
  float* bvec  = v + NV;
  float* cvec  = bvec + (R_ * C_);
  float* bpart = cvec + (R_ * C_);

  for (int it = 0; it < 3; ++it) {
    k_s<<<nseg * 12, 256, 0, stream>>>(x, W, cvec, partial, it > 0 ? 1 : 0, nseg);
    k_sv<<<NV / 256, 256, 0, stream>>>(partial, (it == 2) ? out : v, nseg);
    if (it < 2) {
      k_a<<<128 * 12, 256, 0, stream>>>(x, W, v, bpart);
      k_bc<<<C_, 256, 0, stream>>>(bpart, bvec, cvec, it == 0 ? 1 : 0);
    }
  }
}

// Round 7
// 194.604 us; speedup vs baseline: 1.6955x; 1.6955x over previous
//
#include <hip/hip_runtime.h>

static constexpr int B_ = 256;
static constexpr int R_ = 1152;
static constexpr int C_ = 10;
static constexpr int O_ = 16;
static constexpr int I_ = 8;
static constexpr int SCO = C_ * O_;   // 160
static constexpr int NV = B_ * SCO;   // 40960
static constexpr int NSEG = 128;      // k_s segments
static constexpr int RT_S = R_ / NSEG;    // 9
static constexpr int NSEG_A = 192;    // k_a segments
static constexpr int RT_A = R_ / NSEG_A;  // 6

// ---------------------------------------------------------------------------
// k_s: partial[seg][co][b] = sum_{r in seg} c[r,c(co)] * (W[r,co,:] . x[b,r,:])
// Block = (seg, bq, cg): 64 b x 80 co x 9 r. Lane: bl=t&15 (b-quad), grp=t>>4
// (5 co each). x staged coalesced->LDS [r][i][b pad68]; W per-thread vector
// loads (broadcast over 16 b-lanes). grid = 128*8 = 1024, XCD-swizzled on seg.
// ---------------------------------------------------------------------------
__global__ __launch_bounds__(256, 4) void k_s(const float* __restrict__ x,
                                              const float* __restrict__ W,
                                              const float* __restrict__ cvec,
                                              float* __restrict__ partial,
                                              int use_c) {
  __shared__ float sx[RT_S * 8 * 68];            // 19.6 KB
  const int bx  = blockIdx.x;
  const int seg = ((bx >> 6) << 3) | (bx & 7);   // same-seg blocks share an XCD
  const int sub = (bx >> 3) & 7;
  const int bq = sub >> 1;
  const int cg = sub & 1;
  const int t  = threadIdx.x;
  const int bl  = t & 15;
  const int grp = t >> 4;                        // 0..15
  const int b0  = bq * 64 + bl * 4;
  const int co0 = cg * 80 + grp * 5;
  const int rbase = seg * RT_S;

  // stage x[64b][9r][8i] -> sx[rr][i][b]
#pragma unroll
  for (int k = 0; k < 5; ++k) {
    int idx = t + k * 256;                       // over 64*18 f4
    if (idx < 64 * 18) {
      int b  = idx / 18;
      int f4 = idx - b * 18;
      const float4 val = *(const float4*)(x + (size_t)(bq * 64 + b) * (R_ * I_)
                                            + rbase * I_ + f4 * 4);
      int rr = f4 >> 1, i4 = (f4 & 1) * 4;
      sx[(rr * 8 + i4 + 0) * 68 + b] = val.x;
      sx[(rr * 8 + i4 + 1) * 68 + b] = val.y;
      sx[(rr * 8 + i4 + 2) * 68 + b] = val.z;
      sx[(rr * 8 + i4 + 3) * 68 + b] = val.w;
    }
  }
  __syncthreads();

  const int cA = co0 >> 4;
  const int cB = (co0 + 4) >> 4;
  bool selB[5];
#pragma unroll
  for (int j = 0; j < 5; ++j) selB[j] = ((co0 + j) >> 4) != cA;

  float acc[4][5];
#pragma unroll
  for (int bb = 0; bb < 4; ++bb)
#pragma unroll
    for (int j = 0; j < 5; ++j) acc[bb][j] = 0.0f;

  for (int rr = 0; rr < RT_S; ++rr) {
    const int r = rbase + rr;
    float4 wf[10];
    const float4* wp = (const float4*)(W + (size_t)r * 1280 + co0 * 8);
#pragma unroll
    for (int q = 0; q < 10; ++q) wf[q] = wp[q];
    float cwA = use_c ? cvec[r * C_ + cA] : (1.0f / 1152.0f);
    float cwB = use_c ? cvec[r * C_ + cB] : (1.0f / 1152.0f);
    float4 xv[8];
#pragma unroll
    for (int i = 0; i < 8; ++i)
      xv[i] = *(const float4*)(sx + (rr * 8 + i) * 68 + bl * 4);
    const float* xr = (const float*)xv;          // xr[i*4+bb]
#pragma unroll
    for (int j = 0; j < 5; ++j) {
      const float cw = selB[j] ? cwB : cwA;
      const float* wj = (const float*)&wf[j * 2];
#pragma unroll
      for (int bb = 0; bb < 4; ++bb) {
        float d = wj[0] * xr[bb];
        d = fmaf(wj[1], xr[4 + bb], d);  d = fmaf(wj[2], xr[8 + bb], d);
        d = fmaf(wj[3], xr[12 + bb], d); d = fmaf(wj[4], xr[16 + bb], d);
        d = fmaf(wj[5], xr[20 + bb], d); d = fmaf(wj[6], xr[24 + bb], d);
        d = fmaf(wj[7], xr[28 + bb], d);
        acc[bb][j] = fmaf(cw, d, acc[bb][j]);
      }
    }
  }
  float* pp = partial + (size_t)seg * NV + (size_t)co0 * 256 + b0;
#pragma unroll
  for (int j = 0; j < 5; ++j)
    *(float4*)(pp + j * 256) = make_float4(acc[0][j], acc[1][j], acc[2][j], acc[3][j]);
}

// s = sum over partials; squash v = s*|s|/(1+s^2). v layout [co][b].
// Final pass (direct=1): scatter-transpose to out[b][co].
__global__ __launch_bounds__(256) void k_sv(const float* __restrict__ partial,
                                            float* __restrict__ dst, int direct) {
  const int i = blockIdx.x * 256 + threadIdx.x;  // < NV, i = co*256+b
  float s = 0.0f;
#pragma unroll 8
  for (int g = 0; g < NSEG; ++g) s += partial[(size_t)g * NV + i];
  float val = s * fabsf(s) / (1.0f + s * s);
  if (direct) dst[(i & 255) * SCO + (i >> 8)] = val;   // out[b][co]
  else        dst[i] = val;                            // v[co][b]
}

// ---------------------------------------------------------------------------
// k_a: bpart[bq][r][c] = sum_{b in bq} sum_o (W[r,c,o,:].x[b,r,:]) * v[b,c,o]
// Block = (seg of 6 r, bq): lane bl=t&15 (b-quad), grp=t>>4 = o (16 groups),
// each thread covers all 10 c for its o. grid = 192*4 = 768, XCD-swizzled.
// ---------------------------------------------------------------------------
__global__ __launch_bounds__(256, 3) void k_a(const float* __restrict__ x,
                                              const float* __restrict__ W,
                                              const float* __restrict__ v,
                                              float* __restrict__ bpart) {
  __shared__ float sx[RT_A * 8 * 68];            // 13 KB
  __shared__ float red[RT_A][16][10];            // 3.84 KB
  const int bx  = blockIdx.x;
  const int seg = ((bx >> 5) << 3) | (bx & 7);   // 0..191
  const int bq  = (bx >> 3) & 3;
  const int t   = threadIdx.x;
  const int bl  = t & 15;
  const int grp = t >> 4;                        // o
  const int b0  = bq * 64 + bl * 4;
  const int rbase = seg * RT_A;

  // stage x[64b][6r][8i]
#pragma unroll
  for (int k = 0; k < 3; ++k) {
    int idx = t + k * 256;                       // over 64*12 f4
    int b  = idx / 12;
    int f4 = idx - b * 12;
    const float4 val = *(const float4*)(x + (size_t)(bq * 64 + b) * (R_ * I_)
                                          + rbase * I_ + f4 * 4);
    int rr = f4 >> 1, i4 = (f4 & 1) * 4;
    sx[(rr * 8 + i4 + 0) * 68 + b] = val.x;
    sx[(rr * 8 + i4 + 1) * 68 + b] = val.y;
    sx[(rr * 8 + i4 + 2) * 68 + b] = val.z;
    sx[(rr * 8 + i4 + 3) * 68 + b] = val.w;
  }

  float4 vf[10];                                 // v[c=j][o=grp][b0..3]
#pragma unroll
  for (int j = 0; j < 10; ++j)
    vf[j] = *(const float4*)(v + (size_t)(j * 16 + grp) * 256 + b0);
  __syncthreads();

  for (int rr = 0; rr < RT_A; ++rr) {
    const int r = rbase + rr;
    float4 xv[8];
#pragma unroll
    for (int i = 0; i < 8; ++i)
      xv[i] = *(const float4*)(sx + (rr * 8 + i) * 68 + bl * 4);
    const float* xr = (const float*)xv;
    float p[10];
#pragma unroll
    for (int j = 0; j < 10; ++j) {
      const float* wj = W + (size_t)((r * C_ + j) * O_ + grp) * I_;
      float4 w0 = *(const float4*)wj, w1 = *(const float4*)(wj + 4);
      const float* vfj = (const float*)&vf[j];
      float a = 0.0f;
#pragma unroll
      for (int bb = 0; bb < 4; ++bb) {
        float d = w0.x * xr[bb];
        d = fmaf(w0.y, xr[4 + bb], d);  d = fmaf(w0.z, xr[8 + bb], d);
        d = fmaf(w0.w, xr[12 + bb], d); d = fmaf(w1.x, xr[16 + bb], d);
        d = fmaf(w1.y, xr[20 + bb], d); d = fmaf(w1.z, xr[24 + bb], d);
        d = fmaf(w1.w, xr[28 + bb], d);
        a = fmaf(d, vfj[bb], a);
      }
      p[j] = a;
    }
#pragma unroll
    for (int j = 0; j < 10; ++j) {
      float a = p[j];
      a += __shfl_xor(a, 1); a += __shfl_xor(a, 2);
      a += __shfl_xor(a, 4); a += __shfl_xor(a, 8);
      p[j] = a;
    }
    if (bl == 0) {
#pragma unroll
      for (int j = 0; j < 10; ++j) red[rr][grp][j] = p[j];
    }
  }
  __syncthreads();
  if (t < RT_A * 10) {
    const int rr = t / 10, c = t - rr * 10;
    float s = 0.0f;
#pragma unroll
    for (int g = 0; g < 16; ++g) s += red[rr][g][c];
    bpart[((size_t)bq * R_ + (rbase + rr)) * C_ + c] = s;
  }
}

// b_new = (first ? 0 : b_prev) + (sum_bq bpart)/256; cvec = softmax over r per c.
__global__ __launch_bounds__(256) void k_bc(const float* __restrict__ bpart,
                                            float* __restrict__ bvec,
                                            float* __restrict__ cvec, int first) {
  const int c = blockIdx.x;
  const int t = threadIdx.x;
  __shared__ float smx[4];
  __shared__ float sms[4];
  float bv[5];
  float mx = -3.402823466e38f;
#pragma unroll
  for (int k = 0; k < 5; ++k) {
    int r = t + k * 256;
    if (r < R_) {
      float s = bpart[(size_t)r * C_ + c]
              + bpart[((size_t)R_ + r) * C_ + c]
              + bpart[((size_t)2 * R_ + r) * C_ + c]
              + bpart[((size_t)3 * R_ + r) * C_ + c];
      float val = s * (1.0f / 256.0f);
      if (!first) val += bvec[r * C_ + c];
      bvec[r * C_ + c] = val;
      bv[k] = val;
      mx = fmaxf(mx, val);
    }
  }
  mx = fmaxf(mx, __shfl_xor(mx, 1));  mx = fmaxf(mx, __shfl_xor(mx, 2));
  mx = fmaxf(mx, __shfl_xor(mx, 4));  mx = fmaxf(mx, __shfl_xor(mx, 8));
  mx = fmaxf(mx, __shfl_xor(mx, 16)); mx = fmaxf(mx, __shfl_xor(mx, 32));
  if ((t & 63) == 0) smx[t >> 6] = mx;
  __syncthreads();
  float MX = fmaxf(fmaxf(smx[0], smx[1]), fmaxf(smx[2], smx[3]));
  float se = 0.0f;
  float ef[5];
#pragma unroll
  for (int k = 0; k < 5; ++k) {
    int r = t + k * 256;
    if (r < R_) { ef[k] = expf(bv[k] - MX); se += ef[k]; }
  }
  se += __shfl_xor(se, 1);  se += __shfl_xor(se, 2);  se += __shfl_xor(se, 4);
  se += __shfl_xor(se, 8);  se += __shfl_xor(se, 16); se += __shfl_xor(se, 32);
  if ((t & 63) == 0) sms[t >> 6] = se;
  __syncthreads();
  float inv = 1.0f / ((sms[0] + sms[1]) + (sms[2] + sms[3]));
#pragma unroll
  for (int k = 0; k < 5; ++k) {
    int r = t + k * 256;
    if (r < R_) cvec[r * C_ + c] = ef[k] * inv;
  }
}

extern "C" void kernel_launch(void* const* d_in, const int* in_sizes, int n_in,
                              void* d_out, int out_size, void* d_ws, size_t ws_size,
                              hipStream_t stream) {
  const float* x = (const float*)d_in[0];  // (B,R,I) fp32
  const float* W = (const float*)d_in[1];  // (R,C,O,I) fp32
  float* out = (float*)d_out;              // (B,C,O,1) fp32
  float* ws = (float*)d_ws;                // needs ~21.5 MB (ws is ~268 MB)

  float* partial = ws;                         // NSEG * NV
  float* v     = partial + (size_t)NSEG * NV;  // NV, layout [co][b]
  float* bvec  = v + NV;
  float* cvec  = bvec + (R_ * C_);
  float* bpart = cvec + (R_ * C_);             // 4 * R * C

  for (int it = 0; it < 3; ++it) {
    k_s<<<NSEG * 8, 256, 0, stream>>>(x, W, cvec, partial, it > 0 ? 1 : 0);
    k_sv<<<NV / 256, 256, 0, stream>>>(partial, (it == 2) ? out : v, it == 2 ? 1 : 0);
    if (it < 2) {
      k_a<<<NSEG_A * 4, 256, 0, stream>>>(x, W, v, bpart);
      k_bc<<<C_, 256, 0, stream>>>(bpart, bvec, cvec, it == 0 ? 1 : 0);
    }
  }
}